// Round 12
// baseline (170.091 us; speedup 1.0000x reference)
//
#include <hip/hip_runtime.h>
#include <hip/hip_bf16.h>
#include <math.h>

typedef __attribute__((ext_vector_type(8)))  short bf16x8;
typedef __attribute__((ext_vector_type(4)))  float f32x4;
typedef __attribute__((ext_vector_type(16))) float f32x16;

#define S128 0.08838834764831845f   // 1/sqrt(128)
#define S96  0.10206207261596575f   // 1/sqrt(96)
#define S32  0.17677669529663687f   // 1/sqrt(32)
#define S64  0.125f                 // 1/sqrt(64)
#define NE   40000

__device__ __forceinline__ float silu_f(float x){ return x / (1.0f + expf(-x)); }
__device__ __forceinline__ ushort f2b(float x){
    __hip_bfloat16 b = __float2bfloat16(x); return *(ushort*)&b;
}
__device__ __forceinline__ float b2f(ushort u){
    return __uint_as_float(((uint)u) << 16);
}
__device__ __forceinline__ uint packbf(float a, float b){
    return (uint)f2b(a) | ((uint)f2b(b) << 16);
}

// ---------------------------------------------------------------------------
// prep: WnT [32][128], W1T [128][96], W2T [128][128] (bf16 transposes)
// ---------------------------------------------------------------------------
__global__ __launch_bounds__(256)
void prep_weights(const float* __restrict__ Wn, const float* __restrict__ W1,
                  const float* __restrict__ W2, ushort* __restrict__ WnT,
                  ushort* __restrict__ W1T, ushort* __restrict__ W2T) {
    int idx = blockIdx.x * 256 + threadIdx.x;   // 128 blocks -> 32768
    if (idx < 4096) {
        int n = idx >> 7, k = idx & 127;
        WnT[n * 128 + k] = f2b(Wn[k * 32 + n]);
    } else if (idx < 16384) {
        int t = idx - 4096; int n = t / 96, k = t - n * 96;
        W1T[n * 96 + k] = f2b(W1[k * 128 + n]);
    } else {
        int t = idx - 16384; int n = t >> 7, k = t & 127;
        W2T[n * 128 + k] = f2b(W2[k * 128 + n]);
    }
}

// ---------------------------------------------------------------------------
// W3 [128][5120] f32 -> w3A fragment-major bf16, PRE-SCALED by S128:
//   w3A[pu*4096 + ks*512 + lane*8 + i] = S128 * W3[ks*16+(lane>>5)*8+i][pu*32+(lane&31)]
// ---------------------------------------------------------------------------
__global__ __launch_bounds__(256)
void w3_fragpack(const float* __restrict__ W3, ushort* __restrict__ w3A) {
    const int pu = blockIdx.x;
    const int t  = threadIdx.x;
    #pragma unroll
    for (int s = 0; s < 2; ++s) {
        int slot = s * 256 + t;          // 0..511
        int ks = slot >> 6, l = slot & 63;
        int m = pu * 32 + (l & 31);
        int kbase = ks * 16 + (l >> 5) * 8;
        bf16x8 v;
        #pragma unroll
        for (int i = 0; i < 8; ++i)
            v[i] = (short)f2b(W3[(size_t)(kbase + i) * 5120 + m] * S128);
        *(bf16x8*)&w3A[((size_t)(pu * 8 + ks) * 64 + l) * 8] = v;
    }
}

// ---------------------------------------------------------------------------
// MLP_H2: MLP only -> h2 image (XOR-swizzled, [tile][64*128] bf16) to global.
// ---------------------------------------------------------------------------
__global__ __launch_bounds__(512, 6)
void mlp_h2(const float* __restrict__ ef,  const float* __restrict__ nfs,
            const float* __restrict__ nfr, const ushort* __restrict__ WnT,
            const ushort* __restrict__ W1T, const ushort* __restrict__ W2T,
            ushort* __restrict__ h2img)
{
    __shared__ __align__(16) ushort scratch[15360]; // scal [64][104] | h1b [64][136]
    __shared__ __align__(16) ushort h2s[64 * 128];

    const int tid  = threadIdx.x;
    const int lane = tid & 63, wv = tid >> 6;
    const int l15  = lane & 15, lg = lane >> 4;
    const int tile = blockIdx.x;
    const int e0   = tile * 64;

    ushort* scal = scratch;
    ushort* h1b  = scratch + 6656;

    // ef -> scal cols 64..95
    #pragma unroll
    for (int q = 0; q < 4; ++q) {
        int idx = q * 512 + tid;
        int e = idx >> 5, j = idx & 31;
        scal[e * 104 + 64 + j] = f2b(ef[(size_t)(e0 + e) * 32 + j]);
    }

    // step 1
    {
        const int h = wv >> 2, eb = (wv & 3) * 16;
        const float* src = h ? nfr : nfs;
        const size_t erow = (size_t)(e0 + eb + l15) * 128;
        f32x4 acc1[2] = {{0,0,0,0},{0,0,0,0}};
        #pragma unroll
        for (int ks = 0; ks < 4; ++ks) {
            float4 va = *(const float4*)(src + erow + ks * 32 + lg * 8);
            float4 vb = *(const float4*)(src + erow + ks * 32 + lg * 8 + 4);
            bf16x8 a;
            a[0]=(short)f2b(va.x); a[1]=(short)f2b(va.y);
            a[2]=(short)f2b(va.z); a[3]=(short)f2b(va.w);
            a[4]=(short)f2b(vb.x); a[5]=(short)f2b(vb.y);
            a[6]=(short)f2b(vb.z); a[7]=(short)f2b(vb.w);
            #pragma unroll
            for (int nf = 0; nf < 2; ++nf) {
                bf16x8 b = *(const bf16x8*)(WnT + (nf * 16 + l15) * 128 + ks * 32 + lg * 8);
                acc1[nf] = __builtin_amdgcn_mfma_f32_16x16x32_bf16(a, b, acc1[nf], 0, 0, 0);
            }
        }
        #pragma unroll
        for (int nf = 0; nf < 2; ++nf)
            #pragma unroll
            for (int r = 0; r < 4; ++r)
                scal[(eb + lg * 4 + r) * 104 + h * 32 + nf * 16 + l15] =
                    f2b(acc1[nf][r] * S128);
    }
    __syncthreads();

    // step 2
    {
        const int et = wv & 3, nh = wv >> 2;
        f32x4 acc2[4] = {{0,0,0,0},{0,0,0,0},{0,0,0,0},{0,0,0,0}};
        #pragma unroll
        for (int ks = 0; ks < 3; ++ks) {
            bf16x8 a = *(const bf16x8*)&scal[(et * 16 + l15) * 104 + ks * 32 + lg * 8];
            #pragma unroll
            for (int nf = 0; nf < 4; ++nf) {
                int gn = nh * 4 + nf;
                bf16x8 b = *(const bf16x8*)(W1T + (gn * 16 + l15) * 96 + ks * 32 + lg * 8);
                acc2[nf] = __builtin_amdgcn_mfma_f32_16x16x32_bf16(a, b, acc2[nf], 0, 0, 0);
            }
        }
        #pragma unroll
        for (int nf = 0; nf < 4; ++nf)
            #pragma unroll
            for (int r = 0; r < 4; ++r)
                h1b[(et * 16 + lg * 4 + r) * 136 + (nh * 4 + nf) * 16 + l15] =
                    f2b(silu_f(acc2[nf][r] * S96));
    }
    __syncthreads();

    // step 3 -> h2s XOR-swizzled
    {
        const int et = wv & 3, nh = wv >> 2;
        f32x4 acc3[4] = {{0,0,0,0},{0,0,0,0},{0,0,0,0},{0,0,0,0}};
        #pragma unroll
        for (int ks = 0; ks < 4; ++ks) {
            bf16x8 a = *(const bf16x8*)&h1b[(et * 16 + l15) * 136 + ks * 32 + lg * 8];
            #pragma unroll
            for (int nf = 0; nf < 4; ++nf) {
                int gn = nh * 4 + nf;
                bf16x8 b = *(const bf16x8*)(W2T + (gn * 16 + l15) * 128 + ks * 32 + lg * 8);
                acc3[nf] = __builtin_amdgcn_mfma_f32_16x16x32_bf16(a, b, acc3[nf], 0, 0, 0);
            }
        }
        #pragma unroll
        for (int nf = 0; nf < 4; ++nf)
            #pragma unroll
            for (int r = 0; r < 4; ++r) {
                int e = et * 16 + lg * 4 + r;
                int col = (nh * 4 + nf) * 16 + l15;
                h2s[e * 128 + (col ^ ((e & 15) << 3))] =
                    f2b(silu_f(acc3[nf][r] * S128));
            }
    }
    __syncthreads();

    // coalesced copy out
    #pragma unroll
    for (int it = 0; it < 2; ++it) {
        int idx = it * 512 + tid;    // 1024 chunks of 8
        *(bf16x8*)(h2img + (size_t)tile * 8192 + idx * 8) =
            *(const bf16x8*)&h2s[idx * 8];
    }
}

// ---------------------------------------------------------------------------
// GEMM2: per block = one 64-edge tile x one pu-half (80 pu). Grid 1250.
// B from LDS (h2 image), per-unit a[8], f32 fragment-order x2 tail (float4).
// ---------------------------------------------------------------------------
__global__ __launch_bounds__(512, 6)
void gemm2(const float* __restrict__ em2, const ushort* __restrict__ w3A,
           const ushort* __restrict__ h2img, ushort* __restrict__ dt)
{
    __shared__ __align__(16) ushort hbuf[64 * 128];  // 16384 B
    __shared__ __align__(16) float  x2f[64 * 132];   // 33792 B

    const int tid  = threadIdx.x;
    const int lane = tid & 63, wv = tid >> 6;
    const int tile = blockIdx.x >> 1;
    const int half = blockIdx.x & 1;
    const int e0   = tile * 64;

    // stage h2 image (coalesced)
    #pragma unroll
    for (int it = 0; it < 2; ++it) {
        int idx = it * 512 + tid;
        *(bf16x8*)&hbuf[idx * 8] =
            *(const bf16x8*)(h2img + (size_t)tile * 8192 + idx * 8);
    }
    // stage x2 fragment-order f32
    {
        int e = tid >> 3, grp = tid & 7;
        const float* xr = em2 + (size_t)(e0 + e) * 128;
        float* dst = &x2f[e * 132];
        #pragma unroll
        for (int r = 0; r < 16; ++r) {
            int idx = grp * 16 + r;
            int reg = idx & 15;
            int vb = (reg & 3) + 8 * (reg >> 2);
            float val;
            if (idx < 32) {
                int hi2 = idx >> 4;
                val = xr[vb + 4 * hi2];
            } else {
                int slot = (idx - 32) >> 4;
                int j = slot >> 1, hi2 = slot & 1;
                val = xr[32 + (vb + 4 * hi2) * 3 + j];
            }
            dst[idx] = val;
        }
    }
    __syncthreads();

    const int el  = lane & 31;
    const int hi  = lane >> 5;
    const int sw0 = (el & 15) << 3;
    const float* x2r0 = &x2f[el * 132];
    const float* x2r1 = &x2f[(32 + el) * 132];

    #pragma unroll 1
    for (int un = 0; un < 10; ++un) {
        const int pu = half * 80 + un * 8 + wv;   // wave-uniform
        const int p = pu >> 5, u = pu & 31;
        const ushort* Ab = w3A + (size_t)pu * 4096 + lane * 8;

        bf16x8 a[8];
        #pragma unroll
        for (int ks = 0; ks < 8; ++ks)
            a[ks] = *(const bf16x8*)(Ab + ks * 512);

        #pragma unroll 1
        for (int eh = 0; eh < 2; ++eh) {
            const ushort* hrow = &hbuf[(eh * 32 + el) * 128];
            f32x16 acc = {0,0,0,0,0,0,0,0,0,0,0,0,0,0,0,0};
            #pragma unroll
            for (int ks = 0; ks < 8; ++ks) {
                bf16x8 b = *(const bf16x8*)&hrow[(ks * 16 + hi * 8) ^ sw0];
                acc = __builtin_amdgcn_mfma_f32_32x32x16_bf16(a[ks], b, acc, 0, 0, 0);
            }
            const float* xr = eh ? x2r1 : x2r0;
            const int ecol = e0 + eh * 32 + el;
            if (p == 0 || p == 2) {
                float s = 0.f;
                #pragma unroll
                for (int g4 = 0; g4 < 4; ++g4) {
                    float4 q = *(const float4*)&xr[hi * 16 + g4 * 4];
                    s += acc[4*g4]*q.x + acc[4*g4+1]*q.y
                       + acc[4*g4+2]*q.z + acc[4*g4+3]*q.w;
                }
                s += __shfl_xor(s, 32);
                if (hi == 0)
                    dt[(size_t)(((p == 0) ? 0 : 128) + u) * NE + ecol] = f2b(s);
            } else {
                const int row0 = ((p == 1) ? 32 : (p == 3) ? 160 : 256) + u * 3;
                #pragma unroll
                for (int j = 0; j < 3; ++j) {
                    float s = 0.f;
                    #pragma unroll
                    for (int g4 = 0; g4 < 4; ++g4) {
                        float4 q = *(const float4*)&xr[32 + (j * 2 + hi) * 16 + g4 * 4];
                        s += acc[4*g4]*q.x + acc[4*g4+1]*q.y
                           + acc[4*g4+2]*q.z + acc[4*g4+3]*q.w;
                    }
                    s += __shfl_xor(s, 32);
                    if (hi == 0)
                        dt[(size_t)(row0 + j) * NE + ecol] = f2b(s);
                }
            }
        }
    }
}

// ---------------------------------------------------------------------------
// FINALIZE2: d_t + em1 -> c-values -> output matmuls. 32 edges/block, 4 waves.
// ---------------------------------------------------------------------------
__global__ __launch_bounds__(256)
void finalize2(const float* __restrict__ em1, const ushort* __restrict__ dt,
               const float* __restrict__ W0e, const float* __restrict__ W1o,
               const float* __restrict__ W1e, float* __restrict__ out)
{
    __shared__ __align__(16) ushort dl[352 * 33];   // 23232 B
    __shared__ __align__(16) ushort x1b[32 * 132];  // 8448 B
    const int tid  = threadIdx.x;
    const int lane = tid & 63, wv = tid >> 6;
    const int l15  = lane & 15, lg = lane >> 4;
    const int eb   = blockIdx.x * 32;

    for (int idx = tid; idx < 352 * 32; idx += 256) {
        int row = idx >> 5, e = idx & 31;
        dl[row * 33 + e] = dt[(size_t)row * NE + eb + e];
    }
    {
        int e = tid >> 3, seg = tid & 7;
        const float* x1 = em1 + (size_t)(eb + e) * 128 + seg * 16;
        #pragma unroll
        for (int q = 0; q < 4; ++q) {
            float4 v = *(const float4*)(x1 + q * 4);
            *(uint*)&x1b[e * 132 + seg * 16 + q * 4]     = packbf(v.x, v.y);
            *(uint*)&x1b[e * 132 + seg * 16 + q * 4 + 2] = packbf(v.z, v.w);
        }
    }
    __syncthreads();

    #pragma unroll 1
    for (int it = 0; it < 4; ++it) {
        int unit = it * 4 + wv;
        if (unit >= 14) break;
        int mi = unit & 1, task = unit >> 1;
        const int ei = mi * 16 + l15;
        const ushort* xe = &x1b[ei * 132];
        const size_t orow = (size_t)(eb + mi * 16 + lg * 4) * 224;

        if (task == 0) {                       // out_0e: K = [c1|c4]
            bf16x8 af0, af1;
            #pragma unroll
            for (int t = 0; t < 8; ++t) {
                int u = lg * 8 + t;
                af0[t] = (short)f2b(S32 * b2f(xe[u]) * b2f(dl[u * 33 + ei]));
                float c4 = 0.f;
                #pragma unroll
                for (int i = 0; i < 3; ++i)
                    c4 += b2f(xe[32 + u * 3 + i]) * b2f(dl[(160 + u * 3 + i) * 33 + ei]);
                af1[t] = (short)f2b(c4 * S96);
            }
            #pragma unroll
            for (int nf = 0; nf < 2; ++nf) {
                bf16x8 bf0, bf1;
                #pragma unroll
                for (int t = 0; t < 8; ++t) {
                    bf0[t] = (short)f2b(W0e[(lg * 8 + t) * 32 + nf * 16 + l15]);
                    bf1[t] = (short)f2b(W0e[(32 + lg * 8 + t) * 32 + nf * 16 + l15]);
                }
                f32x4 o = {0.f, 0.f, 0.f, 0.f};
                o = __builtin_amdgcn_mfma_f32_16x16x32_bf16(af0, bf0, o, 0, 0, 0);
                o = __builtin_amdgcn_mfma_f32_16x16x32_bf16(af1, bf1, o, 0, 0, 0);
                #pragma unroll
                for (int rr = 0; rr < 4; ++rr)
                    out[orow + (size_t)rr * 224 + nf * 16 + l15] = o[rr] * S64;
            }
        } else if (task <= 3) {                // out_1o, j = task-1: K = [c2|c3]
            int j = task - 1;
            bf16x8 af0, af1;
            #pragma unroll
            for (int t = 0; t < 8; ++t) {
                int u = lg * 8 + t;
                af0[t] = (short)f2b(S32 * b2f(xe[u]) * b2f(dl[(32 + u * 3 + j) * 33 + ei]));
                af1[t] = (short)f2b(S32 * b2f(xe[32 + u * 3 + j]) * b2f(dl[(128 + u) * 33 + ei]));
            }
            #pragma unroll
            for (int nf = 0; nf < 2; ++nf) {
                bf16x8 bf0, bf1;
                #pragma unroll
                for (int t = 0; t < 8; ++t) {
                    bf0[t] = (short)f2b(W1o[(lg * 8 + t) * 32 + nf * 16 + l15]);
                    bf1[t] = (short)f2b(W1o[(32 + lg * 8 + t) * 32 + nf * 16 + l15]);
                }
                f32x4 o = {0.f, 0.f, 0.f, 0.f};
                o = __builtin_amdgcn_mfma_f32_16x16x32_bf16(af0, bf0, o, 0, 0, 0);
                o = __builtin_amdgcn_mfma_f32_16x16x32_bf16(af1, bf1, o, 0, 0, 0);
                #pragma unroll
                for (int rr = 0; rr < 4; ++rr)
                    out[orow + (size_t)rr * 224 + 32 + (nf * 16 + l15) * 3 + j] = o[rr] * S64;
            }
        } else {                               // out_1e, k = task-4: K = c5
            int k = task - 4;
            int k1 = k + 1; if (k1 > 2) k1 -= 3;
            int k2 = k + 2; if (k2 > 2) k2 -= 3;
            bf16x8 af0;
            #pragma unroll
            for (int t = 0; t < 8; ++t) {
                int u = lg * 8 + t;
                float a_ = b2f(xe[32 + u * 3 + k1]) * b2f(dl[(256 + u * 3 + k2) * 33 + ei])
                         - b2f(xe[32 + u * 3 + k2]) * b2f(dl[(256 + u * 3 + k1) * 33 + ei]);
                af0[t] = (short)f2b(a_ * S64);
            }
            #pragma unroll
            for (int nf = 0; nf < 2; ++nf) {
                bf16x8 bf0;
                #pragma unroll
                for (int t = 0; t < 8; ++t)
                    bf0[t] = (short)f2b(W1e[(lg * 8 + t) * 32 + nf * 16 + l15]);
                f32x4 o = {0.f, 0.f, 0.f, 0.f};
                o = __builtin_amdgcn_mfma_f32_16x16x32_bf16(af0, bf0, o, 0, 0, 0);
                #pragma unroll
                for (int rr = 0; rr < 4; ++rr)
                    out[orow + (size_t)rr * 224 + 128 + (nf * 16 + l15) * 3 + k] = o[rr] * S32;
            }
        }
    }
}

// ---------------------------------------------------------------------------
extern "C" void kernel_launch(void* const* d_in, const int* in_sizes, int n_in,
                              void* d_out, int out_size, void* d_ws, size_t ws_size,
                              hipStream_t stream) {
    const float* ef  = (const float*)d_in[0];
    const float* em1 = (const float*)d_in[1];
    const float* em2 = (const float*)d_in[2];
    const float* nfs = (const float*)d_in[3];
    const float* nfr = (const float*)d_in[4];
    const float* Wn  = (const float*)d_in[5];
    const float* W1  = (const float*)d_in[6];
    const float* W2  = (const float*)d_in[7];
    const float* W3  = (const float*)d_in[8];
    const float* W0e = (const float*)d_in[9];
    const float* W1o = (const float*)d_in[10];
    const float* W1e = (const float*)d_in[11];
    float* out = (float*)d_out;

    const int E = in_sizes[0] / 32;   // 40000

    // ws: w3A [160*8*64*8] | WnT | W1T | W2T | d_t [352][E] | h2img [625*8192]
    char* ws = (char*)d_ws;
    ushort* w3A = (ushort*)ws;
    size_t off = (size_t)5120 * 128 * 2;
    ushort* WnT = (ushort*)(ws + off);  off += 32 * 128 * 2;
    ushort* W1T = (ushort*)(ws + off);  off += 128 * 96 * 2;
    ushort* W2T = (ushort*)(ws + off);  off += 128 * 128 * 2;
    ushort* dt  = (ushort*)(ws + off);  off += (size_t)352 * E * 2;
    ushort* h2img = (ushort*)(ws + off);  // 625*8192*2 = 10.2 MB

    prep_weights<<<128, 256, 0, stream>>>(Wn, W1, W2, WnT, W1T, W2T);
    w3_fragpack<<<160, 256, 0, stream>>>(W3, w3A);
    mlp_h2<<<E / 64, 512, 0, stream>>>(ef, nfs, nfr, WnT, W1T, W2T, h2img);
    gemm2<<<2 * (E / 64), 512, 0, stream>>>(em2, w3A, h2img, dt);
    finalize2<<<E / 32, 256, 0, stream>>>(em1, dt, W0e, W1o, W1e, out);
}

// Round 13
// 166.993 us; speedup vs baseline: 1.0186x; 1.0186x over previous
//
#include <hip/hip_runtime.h>
#include <hip/hip_bf16.h>
#include <math.h>

typedef __attribute__((ext_vector_type(8)))  short bf16x8;
typedef __attribute__((ext_vector_type(4)))  float f32x4;
typedef __attribute__((ext_vector_type(16))) float f32x16;

#define S128 0.08838834764831845f   // 1/sqrt(128)
#define S96  0.10206207261596575f   // 1/sqrt(96)
#define S32  0.17677669529663687f   // 1/sqrt(32)
#define S64  0.125f                 // 1/sqrt(64)
#define NE   40000

__device__ __forceinline__ float silu_f(float x){ return x / (1.0f + expf(-x)); }
__device__ __forceinline__ ushort f2b(float x){
    __hip_bfloat16 b = __float2bfloat16(x); return *(ushort*)&b;
}
__device__ __forceinline__ float b2f(ushort u){
    return __uint_as_float(((uint)u) << 16);
}
__device__ __forceinline__ uint packbf(float a, float b){
    return (uint)f2b(a) | ((uint)f2b(b) << 16);
}

// ---------------------------------------------------------------------------
// prep: WnT [32][128], W1T [128][96], W2T [128][128] (bf16 transposes)
// ---------------------------------------------------------------------------
__global__ __launch_bounds__(256)
void prep_weights(const float* __restrict__ Wn, const float* __restrict__ W1,
                  const float* __restrict__ W2, ushort* __restrict__ WnT,
                  ushort* __restrict__ W1T, ushort* __restrict__ W2T) {
    int idx = blockIdx.x * 256 + threadIdx.x;   // 128 blocks -> 32768
    if (idx < 4096) {
        int n = idx >> 7, k = idx & 127;
        WnT[n * 128 + k] = f2b(Wn[k * 32 + n]);
    } else if (idx < 16384) {
        int t = idx - 4096; int n = t / 96, k = t - n * 96;
        W1T[n * 96 + k] = f2b(W1[k * 128 + n]);
    } else {
        int t = idx - 16384; int n = t >> 7, k = t & 127;
        W2T[n * 128 + k] = f2b(W2[k * 128 + n]);
    }
}

// ---------------------------------------------------------------------------
// W3 [128][5120] f32 -> w3A fragment-major bf16, PRE-SCALED by S128:
//   w3A[pu*4096 + ks*512 + lane*8 + i] = S128 * W3[ks*16+(lane>>5)*8+i][pu*32+(lane&31)]
// ---------------------------------------------------------------------------
__global__ __launch_bounds__(256)
void w3_fragpack(const float* __restrict__ W3, ushort* __restrict__ w3A) {
    const int pu = blockIdx.x;
    const int t  = threadIdx.x;
    #pragma unroll
    for (int s = 0; s < 2; ++s) {
        int slot = s * 256 + t;          // 0..511
        int ks = slot >> 6, l = slot & 63;
        int m = pu * 32 + (l & 31);
        int kbase = ks * 16 + (l >> 5) * 8;
        bf16x8 v;
        #pragma unroll
        for (int i = 0; i < 8; ++i)
            v[i] = (short)f2b(W3[(size_t)(kbase + i) * 5120 + m] * S128);
        *(bf16x8*)&w3A[((size_t)(pu * 8 + ks) * 64 + l) * 8] = v;
    }
}

// ---------------------------------------------------------------------------
// MEGA7: R11 structure (monolithic, B from LDS, per-unit a[8], (512,6),
//        3 blocks/CU) + pre-scaled w3A + float4 tail (x2f stride 132).
// ---------------------------------------------------------------------------
__global__ __launch_bounds__(512, 6)
void mega7(const float* __restrict__ ef,  const float* __restrict__ em2,
           const float* __restrict__ nfs, const float* __restrict__ nfr,
           const ushort* __restrict__ WnT, const ushort* __restrict__ W1T,
           const ushort* __restrict__ W2T, const ushort* __restrict__ w3A,
           ushort* __restrict__ dt)
{
    __shared__ __align__(16) ushort scratch[16896]; // 33792 B: scal|h1b, later x2f
    __shared__ __align__(16) ushort hbuf[64 * 128]; // 16384 B: h2 XOR-swizzled

    const int tid  = threadIdx.x;
    const int lane = tid & 63, wv = tid >> 6;
    const int l15  = lane & 15, lg = lane >> 4;
    const int e0   = blockIdx.x * 64;

    ushort* scal = scratch;          // [64][104]
    ushort* h1b  = scratch + 6656;   // [64][136]
    float*  x2f  = (float*)scratch;  // [64][132] fragment-order (after MLP)

    // ---------- ef -> scal cols 64..95 ----------
    #pragma unroll
    for (int q = 0; q < 4; ++q) {
        int idx = q * 512 + tid;         // 0..2047
        int e = idx >> 5, j = idx & 31;
        scal[e * 104 + 64 + j] = f2b(ef[(size_t)(e0 + e) * 32 + j]);
    }

    // ---------- MLP step 1: s_send/s_recv = nf @ Wn * S128 ----------
    {
        const int h = wv >> 2, eb = (wv & 3) * 16;
        const float* src = h ? nfr : nfs;
        const size_t erow = (size_t)(e0 + eb + l15) * 128;
        f32x4 acc1[2] = {{0,0,0,0},{0,0,0,0}};
        #pragma unroll
        for (int ks = 0; ks < 4; ++ks) {
            float4 va = *(const float4*)(src + erow + ks * 32 + lg * 8);
            float4 vb = *(const float4*)(src + erow + ks * 32 + lg * 8 + 4);
            bf16x8 a;
            a[0]=(short)f2b(va.x); a[1]=(short)f2b(va.y);
            a[2]=(short)f2b(va.z); a[3]=(short)f2b(va.w);
            a[4]=(short)f2b(vb.x); a[5]=(short)f2b(vb.y);
            a[6]=(short)f2b(vb.z); a[7]=(short)f2b(vb.w);
            #pragma unroll
            for (int nf = 0; nf < 2; ++nf) {
                bf16x8 b = *(const bf16x8*)(WnT + (nf * 16 + l15) * 128 + ks * 32 + lg * 8);
                acc1[nf] = __builtin_amdgcn_mfma_f32_16x16x32_bf16(a, b, acc1[nf], 0, 0, 0);
            }
        }
        #pragma unroll
        for (int nf = 0; nf < 2; ++nf)
            #pragma unroll
            for (int r = 0; r < 4; ++r)
                scal[(eb + lg * 4 + r) * 104 + h * 32 + nf * 16 + l15] =
                    f2b(acc1[nf][r] * S128);
    }
    __syncthreads();

    // ---------- MLP step 2: h1 = silu(scal @ W1 * S96) ----------
    {
        const int et = wv & 3, nh = wv >> 2;
        f32x4 acc2[4] = {{0,0,0,0},{0,0,0,0},{0,0,0,0},{0,0,0,0}};
        #pragma unroll
        for (int ks = 0; ks < 3; ++ks) {
            bf16x8 a = *(const bf16x8*)&scal[(et * 16 + l15) * 104 + ks * 32 + lg * 8];
            #pragma unroll
            for (int nf = 0; nf < 4; ++nf) {
                int gn = nh * 4 + nf;
                bf16x8 b = *(const bf16x8*)(W1T + (gn * 16 + l15) * 96 + ks * 32 + lg * 8);
                acc2[nf] = __builtin_amdgcn_mfma_f32_16x16x32_bf16(a, b, acc2[nf], 0, 0, 0);
            }
        }
        #pragma unroll
        for (int nf = 0; nf < 4; ++nf)
            #pragma unroll
            for (int r = 0; r < 4; ++r)
                h1b[(et * 16 + lg * 4 + r) * 136 + (nh * 4 + nf) * 16 + l15] =
                    f2b(silu_f(acc2[nf][r] * S96));
    }
    __syncthreads();

    // ---------- MLP step 3: h2 = silu(h1 @ W2 * S128) -> hbuf XOR-swizzled ----------
    {
        const int et = wv & 3, nh = wv >> 2;
        f32x4 acc3[4] = {{0,0,0,0},{0,0,0,0},{0,0,0,0},{0,0,0,0}};
        #pragma unroll
        for (int ks = 0; ks < 4; ++ks) {
            bf16x8 a = *(const bf16x8*)&h1b[(et * 16 + l15) * 136 + ks * 32 + lg * 8];
            #pragma unroll
            for (int nf = 0; nf < 4; ++nf) {
                int gn = nh * 4 + nf;
                bf16x8 b = *(const bf16x8*)(W2T + (gn * 16 + l15) * 128 + ks * 32 + lg * 8);
                acc3[nf] = __builtin_amdgcn_mfma_f32_16x16x32_bf16(a, b, acc3[nf], 0, 0, 0);
            }
        }
        __syncthreads();   // all h1b/scal reads done before scratch reuse
        #pragma unroll
        for (int nf = 0; nf < 4; ++nf)
            #pragma unroll
            for (int r = 0; r < 4; ++r) {
                int e = et * 16 + lg * 4 + r;
                int col = (nh * 4 + nf) * 16 + l15;
                hbuf[e * 128 + (col ^ ((e & 15) << 3))] =
                    f2b(silu_f(acc3[nf][r] * S128));
            }
    }

    // ---------- stage x2 (em2) as f32 fragment-order into x2f[e][132] ----------
    {
        int e = tid >> 3, grp = tid & 7;
        const float* xr = em2 + (size_t)(e0 + e) * 128;
        float* dst = &x2f[e * 132];
        #pragma unroll
        for (int r = 0; r < 16; ++r) {
            int idx = grp * 16 + r;
            int reg = idx & 15;
            int vb = (reg & 3) + 8 * (reg >> 2);
            float val;
            if (idx < 32) {
                int hi2 = idx >> 4;
                val = xr[vb + 4 * hi2];
            } else {
                int slot = (idx - 32) >> 4;
                int j = slot >> 1, hi2 = slot & 1;
                val = xr[32 + (vb + 4 * hi2) * 3 + j];
            }
            dst[idx] = val;
        }
    }
    __syncthreads();

    // ---------- GEMM: per-unit a[8], B from LDS, float4 f32 tail ----------
    const int el  = lane & 31;
    const int hi  = lane >> 5;
    const int sw0 = (el & 15) << 3;
    const float* x2r0 = &x2f[el * 132];
    const float* x2r1 = &x2f[(32 + el) * 132];

    #pragma unroll 1
    for (int un = 0; un < 20; ++un) {
        const int pu = un * 8 + wv;          // wave-uniform
        const int p = pu >> 5, u = pu & 31;
        const ushort* Ab = w3A + (size_t)pu * 4096 + lane * 8;

        bf16x8 a[8];
        #pragma unroll
        for (int ks = 0; ks < 8; ++ks)
            a[ks] = *(const bf16x8*)(Ab + ks * 512);

        #pragma unroll 1
        for (int eh = 0; eh < 2; ++eh) {
            const ushort* hrow = &hbuf[(eh * 32 + el) * 128];
            f32x16 acc = {0,0,0,0,0,0,0,0,0,0,0,0,0,0,0,0};
            #pragma unroll
            for (int ks = 0; ks < 8; ++ks) {
                bf16x8 b = *(const bf16x8*)&hrow[(ks * 16 + hi * 8) ^ sw0];
                acc = __builtin_amdgcn_mfma_f32_32x32x16_bf16(a[ks], b, acc, 0, 0, 0);
            }
            const float* xr = eh ? x2r1 : x2r0;
            const int ecol = e0 + eh * 32 + el;
            if (p == 0 || p == 2) {
                float s = 0.f;
                #pragma unroll
                for (int g4 = 0; g4 < 4; ++g4) {
                    float4 q = *(const float4*)&xr[hi * 16 + g4 * 4];
                    s += acc[4*g4]*q.x + acc[4*g4+1]*q.y
                       + acc[4*g4+2]*q.z + acc[4*g4+3]*q.w;
                }
                s += __shfl_xor(s, 32);
                if (hi == 0)
                    dt[(size_t)(((p == 0) ? 0 : 128) + u) * NE + ecol] = f2b(s);
            } else {
                const int row0 = ((p == 1) ? 32 : (p == 3) ? 160 : 256) + u * 3;
                #pragma unroll
                for (int j = 0; j < 3; ++j) {
                    float s = 0.f;
                    #pragma unroll
                    for (int g4 = 0; g4 < 4; ++g4) {
                        float4 q = *(const float4*)&xr[32 + (j * 2 + hi) * 16 + g4 * 4];
                        s += acc[4*g4]*q.x + acc[4*g4+1]*q.y
                           + acc[4*g4+2]*q.z + acc[4*g4+3]*q.w;
                    }
                    s += __shfl_xor(s, 32);
                    if (hi == 0)
                        dt[(size_t)(row0 + j) * NE + ecol] = f2b(s);
                }
            }
        }
    }
}

// ---------------------------------------------------------------------------
// FINALIZE2: d_t + em1 -> c-values -> output matmuls. 32 edges/block, 4 waves.
// ---------------------------------------------------------------------------
__global__ __launch_bounds__(256)
void finalize2(const float* __restrict__ em1, const ushort* __restrict__ dt,
               const float* __restrict__ W0e, const float* __restrict__ W1o,
               const float* __restrict__ W1e, float* __restrict__ out)
{
    __shared__ __align__(16) ushort dl[352 * 33];   // 23232 B
    __shared__ __align__(16) ushort x1b[32 * 132];  // 8448 B
    const int tid  = threadIdx.x;
    const int lane = tid & 63, wv = tid >> 6;
    const int l15  = lane & 15, lg = lane >> 4;
    const int eb   = blockIdx.x * 32;

    for (int idx = tid; idx < 352 * 32; idx += 256) {
        int row = idx >> 5, e = idx & 31;
        dl[row * 33 + e] = dt[(size_t)row * NE + eb + e];
    }
    {
        int e = tid >> 3, seg = tid & 7;
        const float* x1 = em1 + (size_t)(eb + e) * 128 + seg * 16;
        #pragma unroll
        for (int q = 0; q < 4; ++q) {
            float4 v = *(const float4*)(x1 + q * 4);
            *(uint*)&x1b[e * 132 + seg * 16 + q * 4]     = packbf(v.x, v.y);
            *(uint*)&x1b[e * 132 + seg * 16 + q * 4 + 2] = packbf(v.z, v.w);
        }
    }
    __syncthreads();

    #pragma unroll 1
    for (int it = 0; it < 4; ++it) {
        int unit = it * 4 + wv;
        if (unit >= 14) break;
        int mi = unit & 1, task = unit >> 1;
        const int ei = mi * 16 + l15;
        const ushort* xe = &x1b[ei * 132];
        const size_t orow = (size_t)(eb + mi * 16 + lg * 4) * 224;

        if (task == 0) {                       // out_0e: K = [c1|c4]
            bf16x8 af0, af1;
            #pragma unroll
            for (int t = 0; t < 8; ++t) {
                int u = lg * 8 + t;
                af0[t] = (short)f2b(S32 * b2f(xe[u]) * b2f(dl[u * 33 + ei]));
                float c4 = 0.f;
                #pragma unroll
                for (int i = 0; i < 3; ++i)
                    c4 += b2f(xe[32 + u * 3 + i]) * b2f(dl[(160 + u * 3 + i) * 33 + ei]);
                af1[t] = (short)f2b(c4 * S96);
            }
            #pragma unroll
            for (int nf = 0; nf < 2; ++nf) {
                bf16x8 bf0, bf1;
                #pragma unroll
                for (int t = 0; t < 8; ++t) {
                    bf0[t] = (short)f2b(W0e[(lg * 8 + t) * 32 + nf * 16 + l15]);
                    bf1[t] = (short)f2b(W0e[(32 + lg * 8 + t) * 32 + nf * 16 + l15]);
                }
                f32x4 o = {0.f, 0.f, 0.f, 0.f};
                o = __builtin_amdgcn_mfma_f32_16x16x32_bf16(af0, bf0, o, 0, 0, 0);
                o = __builtin_amdgcn_mfma_f32_16x16x32_bf16(af1, bf1, o, 0, 0, 0);
                #pragma unroll
                for (int rr = 0; rr < 4; ++rr)
                    out[orow + (size_t)rr * 224 + nf * 16 + l15] = o[rr] * S64;
            }
        } else if (task <= 3) {                // out_1o, j = task-1: K = [c2|c3]
            int j = task - 1;
            bf16x8 af0, af1;
            #pragma unroll
            for (int t = 0; t < 8; ++t) {
                int u = lg * 8 + t;
                af0[t] = (short)f2b(S32 * b2f(xe[u]) * b2f(dl[(32 + u * 3 + j) * 33 + ei]));
                af1[t] = (short)f2b(S32 * b2f(xe[32 + u * 3 + j]) * b2f(dl[(128 + u) * 33 + ei]));
            }
            #pragma unroll
            for (int nf = 0; nf < 2; ++nf) {
                bf16x8 bf0, bf1;
                #pragma unroll
                for (int t = 0; t < 8; ++t) {
                    bf0[t] = (short)f2b(W1o[(lg * 8 + t) * 32 + nf * 16 + l15]);
                    bf1[t] = (short)f2b(W1o[(32 + lg * 8 + t) * 32 + nf * 16 + l15]);
                }
                f32x4 o = {0.f, 0.f, 0.f, 0.f};
                o = __builtin_amdgcn_mfma_f32_16x16x32_bf16(af0, bf0, o, 0, 0, 0);
                o = __builtin_amdgcn_mfma_f32_16x16x32_bf16(af1, bf1, o, 0, 0, 0);
                #pragma unroll
                for (int rr = 0; rr < 4; ++rr)
                    out[orow + (size_t)rr * 224 + 32 + (nf * 16 + l15) * 3 + j] = o[rr] * S64;
            }
        } else {                               // out_1e, k = task-4: K = c5
            int k = task - 4;
            int k1 = k + 1; if (k1 > 2) k1 -= 3;
            int k2 = k + 2; if (k2 > 2) k2 -= 3;
            bf16x8 af0;
            #pragma unroll
            for (int t = 0; t < 8; ++t) {
                int u = lg * 8 + t;
                float a_ = b2f(xe[32 + u * 3 + k1]) * b2f(dl[(256 + u * 3 + k2) * 33 + ei])
                         - b2f(xe[32 + u * 3 + k2]) * b2f(dl[(256 + u * 3 + k1) * 33 + ei]);
                af0[t] = (short)f2b(a_ * S64);
            }
            #pragma unroll
            for (int nf = 0; nf < 2; ++nf) {
                bf16x8 bf0;
                #pragma unroll
                for (int t = 0; t < 8; ++t)
                    bf0[t] = (short)f2b(W1e[(lg * 8 + t) * 32 + nf * 16 + l15]);
                f32x4 o = {0.f, 0.f, 0.f, 0.f};
                o = __builtin_amdgcn_mfma_f32_16x16x32_bf16(af0, bf0, o, 0, 0, 0);
                #pragma unroll
                for (int rr = 0; rr < 4; ++rr)
                    out[orow + (size_t)rr * 224 + 128 + (nf * 16 + l15) * 3 + k] = o[rr] * S32;
            }
        }
    }
}

// ---------------------------------------------------------------------------
extern "C" void kernel_launch(void* const* d_in, const int* in_sizes, int n_in,
                              void* d_out, int out_size, void* d_ws, size_t ws_size,
                              hipStream_t stream) {
    const float* ef  = (const float*)d_in[0];
    const float* em1 = (const float*)d_in[1];
    const float* em2 = (const float*)d_in[2];
    const float* nfs = (const float*)d_in[3];
    const float* nfr = (const float*)d_in[4];
    const float* Wn  = (const float*)d_in[5];
    const float* W1  = (const float*)d_in[6];
    const float* W2  = (const float*)d_in[7];
    const float* W3  = (const float*)d_in[8];
    const float* W0e = (const float*)d_in[9];
    const float* W1o = (const float*)d_in[10];
    const float* W1e = (const float*)d_in[11];
    float* out = (float*)d_out;

    const int E = in_sizes[0] / 32;   // 40000

    // ws: w3A [160*8*64*8] | WnT | W1T | W2T | d_t [352][E]
    char* ws = (char*)d_ws;
    ushort* w3A = (ushort*)ws;
    size_t off = (size_t)5120 * 128 * 2;
    ushort* WnT = (ushort*)(ws + off);  off += 32 * 128 * 2;
    ushort* W1T = (ushort*)(ws + off);  off += 128 * 96 * 2;
    ushort* W2T = (ushort*)(ws + off);  off += 128 * 128 * 2;
    ushort* dt  = (ushort*)(ws + off);  // 352 * E * 2 = 28.2 MB

    prep_weights<<<128, 256, 0, stream>>>(Wn, W1, W2, WnT, W1T, W2T);
    w3_fragpack<<<160, 256, 0, stream>>>(W3, w3A);
    mega7<<<E / 64, 512, 0, stream>>>(ef, em2, nfs, nfr,
                                      WnT, W1T, W2T, w3A, dt);
    finalize2<<<E / 32, 256, 0, stream>>>(em1, dt, W0e, W1o, W1e, out);
}

// Round 14
// 144.154 us; speedup vs baseline: 1.1799x; 1.1584x over previous
//
#include <hip/hip_runtime.h>
#include <hip/hip_bf16.h>
#include <math.h>

typedef __attribute__((ext_vector_type(8)))  short bf16x8;
typedef __attribute__((ext_vector_type(4)))  float f32x4;
typedef __attribute__((ext_vector_type(16))) float f32x16;

#define S128 0.08838834764831845f   // 1/sqrt(128)
#define S96  0.10206207261596575f   // 1/sqrt(96)
#define S32  0.17677669529663687f   // 1/sqrt(32)
#define S64  0.125f                 // 1/sqrt(64)
#define NE   40000

__device__ __forceinline__ float silu_f(float x){ return x / (1.0f + expf(-x)); }
__device__ __forceinline__ ushort f2b(float x){
    __hip_bfloat16 b = __float2bfloat16(x); return *(ushort*)&b;
}
__device__ __forceinline__ float b2f(ushort u){
    return __uint_as_float(((uint)u) << 16);
}
__device__ __forceinline__ uint packbf(float a, float b){
    return (uint)f2b(a) | ((uint)f2b(b) << 16);
}

// ---------------------------------------------------------------------------
// prep: WnT [32][128], W1T [128][96], W2T [128][128] (bf16 transposes)
// ---------------------------------------------------------------------------
__global__ __launch_bounds__(256)
void prep_weights(const float* __restrict__ Wn, const float* __restrict__ W1,
                  const float* __restrict__ W2, ushort* __restrict__ WnT,
                  ushort* __restrict__ W1T, ushort* __restrict__ W2T) {
    int idx = blockIdx.x * 256 + threadIdx.x;   // 128 blocks -> 32768
    if (idx < 4096) {
        int n = idx >> 7, k = idx & 127;
        WnT[n * 128 + k] = f2b(Wn[k * 32 + n]);
    } else if (idx < 16384) {
        int t = idx - 4096; int n = t / 96, k = t - n * 96;
        W1T[n * 96 + k] = f2b(W1[k * 128 + n]);
    } else {
        int t = idx - 16384; int n = t >> 7, k = t & 127;
        W2T[n * 128 + k] = f2b(W2[k * 128 + n]);
    }
}

// ---------------------------------------------------------------------------
// W3 [128][5120] f32 -> w3A fragment-major bf16, PRE-SCALED by S128:
//   w3A[pu*4096 + ks*512 + lane*8 + i] = S128 * W3[ks*16+(lane>>5)*8+i][pu*32+(lane&31)]
// ---------------------------------------------------------------------------
__global__ __launch_bounds__(256)
void w3_fragpack(const float* __restrict__ W3, ushort* __restrict__ w3A) {
    const int pu = blockIdx.x;
    const int t  = threadIdx.x;
    #pragma unroll
    for (int s = 0; s < 2; ++s) {
        int slot = s * 256 + t;          // 0..511
        int ks = slot >> 6, l = slot & 63;
        int m = pu * 32 + (l & 31);
        int kbase = ks * 16 + (l >> 5) * 8;
        bf16x8 v;
        #pragma unroll
        for (int i = 0; i < 8; ++i)
            v[i] = (short)f2b(W3[(size_t)(kbase + i) * 5120 + m] * S128);
        *(bf16x8*)&w3A[((size_t)(pu * 8 + ks) * 64 + l) * 8] = v;
    }
}

// ---------------------------------------------------------------------------
// MEGA8: exact R11 structure (monolithic, B from LDS, per-unit a[8], (512,6),
//        x2f stride 130 + float2 tail) + pre-scaled w3A only.
// ---------------------------------------------------------------------------
__global__ __launch_bounds__(512, 6)
void mega8(const float* __restrict__ ef,  const float* __restrict__ em2,
           const float* __restrict__ nfs, const float* __restrict__ nfr,
           const ushort* __restrict__ WnT, const ushort* __restrict__ W1T,
           const ushort* __restrict__ W2T, const ushort* __restrict__ w3A,
           ushort* __restrict__ dt)
{
    __shared__ __align__(16) ushort scratch[16640]; // 33280 B: scal|h1b, later x2f
    __shared__ __align__(16) ushort hbuf[64 * 128]; // 16384 B: h2 XOR-swizzled

    const int tid  = threadIdx.x;
    const int lane = tid & 63, wv = tid >> 6;
    const int l15  = lane & 15, lg = lane >> 4;
    const int e0   = blockIdx.x * 64;

    ushort* scal = scratch;          // [64][104]
    ushort* h1b  = scratch + 6656;   // [64][136]
    float*  x2f  = (float*)scratch;  // [64][130] fragment-order (after MLP)

    // ---------- ef -> scal cols 64..95 ----------
    #pragma unroll
    for (int q = 0; q < 4; ++q) {
        int idx = q * 512 + tid;         // 0..2047
        int e = idx >> 5, j = idx & 31;
        scal[e * 104 + 64 + j] = f2b(ef[(size_t)(e0 + e) * 32 + j]);
    }

    // ---------- MLP step 1: s_send/s_recv = nf @ Wn * S128 ----------
    {
        const int h = wv >> 2, eb = (wv & 3) * 16;
        const float* src = h ? nfr : nfs;
        const size_t erow = (size_t)(e0 + eb + l15) * 128;
        f32x4 acc1[2] = {{0,0,0,0},{0,0,0,0}};
        #pragma unroll
        for (int ks = 0; ks < 4; ++ks) {
            float4 va = *(const float4*)(src + erow + ks * 32 + lg * 8);
            float4 vb = *(const float4*)(src + erow + ks * 32 + lg * 8 + 4);
            bf16x8 a;
            a[0]=(short)f2b(va.x); a[1]=(short)f2b(va.y);
            a[2]=(short)f2b(va.z); a[3]=(short)f2b(va.w);
            a[4]=(short)f2b(vb.x); a[5]=(short)f2b(vb.y);
            a[6]=(short)f2b(vb.z); a[7]=(short)f2b(vb.w);
            #pragma unroll
            for (int nf = 0; nf < 2; ++nf) {
                bf16x8 b = *(const bf16x8*)(WnT + (nf * 16 + l15) * 128 + ks * 32 + lg * 8);
                acc1[nf] = __builtin_amdgcn_mfma_f32_16x16x32_bf16(a, b, acc1[nf], 0, 0, 0);
            }
        }
        #pragma unroll
        for (int nf = 0; nf < 2; ++nf)
            #pragma unroll
            for (int r = 0; r < 4; ++r)
                scal[(eb + lg * 4 + r) * 104 + h * 32 + nf * 16 + l15] =
                    f2b(acc1[nf][r] * S128);
    }
    __syncthreads();

    // ---------- MLP step 2: h1 = silu(scal @ W1 * S96) ----------
    {
        const int et = wv & 3, nh = wv >> 2;
        f32x4 acc2[4] = {{0,0,0,0},{0,0,0,0},{0,0,0,0},{0,0,0,0}};
        #pragma unroll
        for (int ks = 0; ks < 3; ++ks) {
            bf16x8 a = *(const bf16x8*)&scal[(et * 16 + l15) * 104 + ks * 32 + lg * 8];
            #pragma unroll
            for (int nf = 0; nf < 4; ++nf) {
                int gn = nh * 4 + nf;
                bf16x8 b = *(const bf16x8*)(W1T + (gn * 16 + l15) * 96 + ks * 32 + lg * 8);
                acc2[nf] = __builtin_amdgcn_mfma_f32_16x16x32_bf16(a, b, acc2[nf], 0, 0, 0);
            }
        }
        #pragma unroll
        for (int nf = 0; nf < 4; ++nf)
            #pragma unroll
            for (int r = 0; r < 4; ++r)
                h1b[(et * 16 + lg * 4 + r) * 136 + (nh * 4 + nf) * 16 + l15] =
                    f2b(silu_f(acc2[nf][r] * S96));
    }
    __syncthreads();

    // ---------- MLP step 3: h2 = silu(h1 @ W2 * S128) -> hbuf XOR-swizzled ----------
    {
        const int et = wv & 3, nh = wv >> 2;
        f32x4 acc3[4] = {{0,0,0,0},{0,0,0,0},{0,0,0,0},{0,0,0,0}};
        #pragma unroll
        for (int ks = 0; ks < 4; ++ks) {
            bf16x8 a = *(const bf16x8*)&h1b[(et * 16 + l15) * 136 + ks * 32 + lg * 8];
            #pragma unroll
            for (int nf = 0; nf < 4; ++nf) {
                int gn = nh * 4 + nf;
                bf16x8 b = *(const bf16x8*)(W2T + (gn * 16 + l15) * 128 + ks * 32 + lg * 8);
                acc3[nf] = __builtin_amdgcn_mfma_f32_16x16x32_bf16(a, b, acc3[nf], 0, 0, 0);
            }
        }
        __syncthreads();   // all h1b/scal reads done before scratch reuse
        #pragma unroll
        for (int nf = 0; nf < 4; ++nf)
            #pragma unroll
            for (int r = 0; r < 4; ++r) {
                int e = et * 16 + lg * 4 + r;
                int col = (nh * 4 + nf) * 16 + l15;
                hbuf[e * 128 + (col ^ ((e & 15) << 3))] =
                    f2b(silu_f(acc3[nf][r] * S128));
            }
    }

    // ---------- stage x2 (em2) as f32 fragment-order into x2f[e][130] ----------
    {
        int e = tid >> 3, grp = tid & 7;
        const float* xr = em2 + (size_t)(e0 + e) * 128;
        float* dst = &x2f[e * 130];
        #pragma unroll
        for (int r = 0; r < 16; ++r) {
            int idx = grp * 16 + r;
            int reg = idx & 15;
            int vb = (reg & 3) + 8 * (reg >> 2);
            float val;
            if (idx < 32) {
                int hi2 = idx >> 4;
                val = xr[vb + 4 * hi2];
            } else {
                int slot = (idx - 32) >> 4;
                int j = slot >> 1, hi2 = slot & 1;
                val = xr[32 + (vb + 4 * hi2) * 3 + j];
            }
            dst[idx] = val;
        }
    }
    __syncthreads();

    // ---------- GEMM: per-unit a[8], B from LDS, float2 f32 tail ----------
    const int el  = lane & 31;
    const int hi  = lane >> 5;
    const int sw0 = (el & 15) << 3;
    const float* x2r0 = &x2f[el * 130];
    const float* x2r1 = &x2f[(32 + el) * 130];

    #pragma unroll 1
    for (int un = 0; un < 20; ++un) {
        const int pu = un * 8 + wv;          // wave-uniform
        const int p = pu >> 5, u = pu & 31;
        const ushort* Ab = w3A + (size_t)pu * 4096 + lane * 8;

        bf16x8 a[8];
        #pragma unroll
        for (int ks = 0; ks < 8; ++ks)
            a[ks] = *(const bf16x8*)(Ab + ks * 512);

        #pragma unroll 1
        for (int eh = 0; eh < 2; ++eh) {
            const ushort* hrow = &hbuf[(eh * 32 + el) * 128];
            f32x16 acc = {0,0,0,0,0,0,0,0,0,0,0,0,0,0,0,0};
            #pragma unroll
            for (int ks = 0; ks < 8; ++ks) {
                bf16x8 b = *(const bf16x8*)&hrow[(ks * 16 + hi * 8) ^ sw0];
                acc = __builtin_amdgcn_mfma_f32_32x32x16_bf16(a[ks], b, acc, 0, 0, 0);
            }
            const float* xr = eh ? x2r1 : x2r0;
            const int ecol = e0 + eh * 32 + el;
            if (p == 0 || p == 2) {
                float s = 0.f;
                #pragma unroll
                for (int g = 0; g < 8; ++g) {
                    float2 q = *(const float2*)&xr[hi * 16 + g * 2];
                    s += acc[2*g] * q.x + acc[2*g+1] * q.y;
                }
                s += __shfl_xor(s, 32);
                if (hi == 0)
                    dt[(size_t)(((p == 0) ? 0 : 128) + u) * NE + ecol] = f2b(s);
            } else {
                const int row0 = ((p == 1) ? 32 : (p == 3) ? 160 : 256) + u * 3;
                #pragma unroll
                for (int j = 0; j < 3; ++j) {
                    float s = 0.f;
                    #pragma unroll
                    for (int g = 0; g < 8; ++g) {
                        float2 q = *(const float2*)&xr[32 + (j * 2 + hi) * 16 + g * 2];
                        s += acc[2*g] * q.x + acc[2*g+1] * q.y;
                    }
                    s += __shfl_xor(s, 32);
                    if (hi == 0)
                        dt[(size_t)(row0 + j) * NE + ecol] = f2b(s);
                }
            }
        }
    }
}

// ---------------------------------------------------------------------------
// FINALIZE2: d_t + em1 -> c-values -> output matmuls. 32 edges/block, 4 waves.
// ---------------------------------------------------------------------------
__global__ __launch_bounds__(256)
void finalize2(const float* __restrict__ em1, const ushort* __restrict__ dt,
               const float* __restrict__ W0e, const float* __restrict__ W1o,
               const float* __restrict__ W1e, float* __restrict__ out)
{
    __shared__ __align__(16) ushort dl[352 * 33];   // 23232 B
    __shared__ __align__(16) ushort x1b[32 * 132];  // 8448 B
    const int tid  = threadIdx.x;
    const int lane = tid & 63, wv = tid >> 6;
    const int l15  = lane & 15, lg = lane >> 4;
    const int eb   = blockIdx.x * 32;

    for (int idx = tid; idx < 352 * 32; idx += 256) {
        int row = idx >> 5, e = idx & 31;
        dl[row * 33 + e] = dt[(size_t)row * NE + eb + e];
    }
    {
        int e = tid >> 3, seg = tid & 7;
        const float* x1 = em1 + (size_t)(eb + e) * 128 + seg * 16;
        #pragma unroll
        for (int q = 0; q < 4; ++q) {
            float4 v = *(const float4*)(x1 + q * 4);
            *(uint*)&x1b[e * 132 + seg * 16 + q * 4]     = packbf(v.x, v.y);
            *(uint*)&x1b[e * 132 + seg * 16 + q * 4 + 2] = packbf(v.z, v.w);
        }
    }
    __syncthreads();

    #pragma unroll 1
    for (int it = 0; it < 4; ++it) {
        int unit = it * 4 + wv;
        if (unit >= 14) break;
        int mi = unit & 1, task = unit >> 1;
        const int ei = mi * 16 + l15;
        const ushort* xe = &x1b[ei * 132];
        const size_t orow = (size_t)(eb + mi * 16 + lg * 4) * 224;

        if (task == 0) {                       // out_0e: K = [c1|c4]
            bf16x8 af0, af1;
            #pragma unroll
            for (int t = 0; t < 8; ++t) {
                int u = lg * 8 + t;
                af0[t] = (short)f2b(S32 * b2f(xe[u]) * b2f(dl[u * 33 + ei]));
                float c4 = 0.f;
                #pragma unroll
                for (int i = 0; i < 3; ++i)
                    c4 += b2f(xe[32 + u * 3 + i]) * b2f(dl[(160 + u * 3 + i) * 33 + ei]);
                af1[t] = (short)f2b(c4 * S96);
            }
            #pragma unroll
            for (int nf = 0; nf < 2; ++nf) {
                bf16x8 bf0, bf1;
                #pragma unroll
                for (int t = 0; t < 8; ++t) {
                    bf0[t] = (short)f2b(W0e[(lg * 8 + t) * 32 + nf * 16 + l15]);
                    bf1[t] = (short)f2b(W0e[(32 + lg * 8 + t) * 32 + nf * 16 + l15]);
                }
                f32x4 o = {0.f, 0.f, 0.f, 0.f};
                o = __builtin_amdgcn_mfma_f32_16x16x32_bf16(af0, bf0, o, 0, 0, 0);
                o = __builtin_amdgcn_mfma_f32_16x16x32_bf16(af1, bf1, o, 0, 0, 0);
                #pragma unroll
                for (int rr = 0; rr < 4; ++rr)
                    out[orow + (size_t)rr * 224 + nf * 16 + l15] = o[rr] * S64;
            }
        } else if (task <= 3) {                // out_1o, j = task-1: K = [c2|c3]
            int j = task - 1;
            bf16x8 af0, af1;
            #pragma unroll
            for (int t = 0; t < 8; ++t) {
                int u = lg * 8 + t;
                af0[t] = (short)f2b(S32 * b2f(xe[u]) * b2f(dl[(32 + u * 3 + j) * 33 + ei]));
                af1[t] = (short)f2b(S32 * b2f(xe[32 + u * 3 + j]) * b2f(dl[(128 + u) * 33 + ei]));
            }
            #pragma unroll
            for (int nf = 0; nf < 2; ++nf) {
                bf16x8 bf0, bf1;
                #pragma unroll
                for (int t = 0; t < 8; ++t) {
                    bf0[t] = (short)f2b(W1o[(lg * 8 + t) * 32 + nf * 16 + l15]);
                    bf1[t] = (short)f2b(W1o[(32 + lg * 8 + t) * 32 + nf * 16 + l15]);
                }
                f32x4 o = {0.f, 0.f, 0.f, 0.f};
                o = __builtin_amdgcn_mfma_f32_16x16x32_bf16(af0, bf0, o, 0, 0, 0);
                o = __builtin_amdgcn_mfma_f32_16x16x32_bf16(af1, bf1, o, 0, 0, 0);
                #pragma unroll
                for (int rr = 0; rr < 4; ++rr)
                    out[orow + (size_t)rr * 224 + 32 + (nf * 16 + l15) * 3 + j] = o[rr] * S64;
            }
        } else {                               // out_1e, k = task-4: K = c5
            int k = task - 4;
            int k1 = k + 1; if (k1 > 2) k1 -= 3;
            int k2 = k + 2; if (k2 > 2) k2 -= 3;
            bf16x8 af0;
            #pragma unroll
            for (int t = 0; t < 8; ++t) {
                int u = lg * 8 + t;
                float a_ = b2f(xe[32 + u * 3 + k1]) * b2f(dl[(256 + u * 3 + k2) * 33 + ei])
                         - b2f(xe[32 + u * 3 + k2]) * b2f(dl[(256 + u * 3 + k1) * 33 + ei]);
                af0[t] = (short)f2b(a_ * S64);
            }
            #pragma unroll
            for (int nf = 0; nf < 2; ++nf) {
                bf16x8 bf0;
                #pragma unroll
                for (int t = 0; t < 8; ++t)
                    bf0[t] = (short)f2b(W1e[(lg * 8 + t) * 32 + nf * 16 + l15]);
                f32x4 o = {0.f, 0.f, 0.f, 0.f};
                o = __builtin_amdgcn_mfma_f32_16x16x32_bf16(af0, bf0, o, 0, 0, 0);
                #pragma unroll
                for (int rr = 0; rr < 4; ++rr)
                    out[orow + (size_t)rr * 224 + 128 + (nf * 16 + l15) * 3 + k] = o[rr] * S32;
            }
        }
    }
}

// ---------------------------------------------------------------------------
extern "C" void kernel_launch(void* const* d_in, const int* in_sizes, int n_in,
                              void* d_out, int out_size, void* d_ws, size_t ws_size,
                              hipStream_t stream) {
    const float* ef  = (const float*)d_in[0];
    const float* em1 = (const float*)d_in[1];
    const float* em2 = (const float*)d_in[2];
    const float* nfs = (const float*)d_in[3];
    const float* nfr = (const float*)d_in[4];
    const float* Wn  = (const float*)d_in[5];
    const float* W1  = (const float*)d_in[6];
    const float* W2  = (const float*)d_in[7];
    const float* W3  = (const float*)d_in[8];
    const float* W0e = (const float*)d_in[9];
    const float* W1o = (const float*)d_in[10];
    const float* W1e = (const float*)d_in[11];
    float* out = (float*)d_out;

    const int E = in_sizes[0] / 32;   // 40000

    // ws: w3A [160*8*64*8] | WnT | W1T | W2T | d_t [352][E]
    char* ws = (char*)d_ws;
    ushort* w3A = (ushort*)ws;
    size_t off = (size_t)5120 * 128 * 2;
    ushort* WnT = (ushort*)(ws + off);  off += 32 * 128 * 2;
    ushort* W1T = (ushort*)(ws + off);  off += 128 * 96 * 2;
    ushort* W2T = (ushort*)(ws + off);  off += 128 * 128 * 2;
    ushort* dt  = (ushort*)(ws + off);  // 352 * E * 2 = 28.2 MB

    prep_weights<<<128, 256, 0, stream>>>(Wn, W1, W2, WnT, W1T, W2T);
    w3_fragpack<<<160, 256, 0, stream>>>(W3, w3A);
    mega8<<<E / 64, 512, 0, stream>>>(ef, em2, nfs, nfr,
                                      WnT, W1T, W2T, w3A, dt);
    finalize2<<<E / 32, 256, 0, stream>>>(em1, dt, W0e, W1o, W1e, out);
}

// Round 15
// 141.693 us; speedup vs baseline: 1.2004x; 1.0174x over previous
//
#include <hip/hip_runtime.h>
#include <hip/hip_bf16.h>
#include <math.h>

typedef __attribute__((ext_vector_type(8)))  short bf16x8;
typedef __attribute__((ext_vector_type(4)))  float f32x4;
typedef __attribute__((ext_vector_type(16))) float f32x16;

#define S128 0.08838834764831845f   // 1/sqrt(128)
#define S96  0.10206207261596575f   // 1/sqrt(96)
#define S32  0.17677669529663687f   // 1/sqrt(32)
#define S64  0.125f                 // 1/sqrt(64)
#define NE   40000

__device__ __forceinline__ float silu_f(float x){ return x / (1.0f + expf(-x)); }
__device__ __forceinline__ ushort f2b(float x){
    __hip_bfloat16 b = __float2bfloat16(x); return *(ushort*)&b;
}
__device__ __forceinline__ float b2f(ushort u){
    return __uint_as_float(((uint)u) << 16);
}
__device__ __forceinline__ uint packbf(float a, float b){
    return (uint)f2b(a) | ((uint)f2b(b) << 16);
}

// ---------------------------------------------------------------------------
// PREP_ALL (288 blocks):
//  blocks 0..159  : w3A fragment-pack for pu=blockIdx (LDS-staged, coalesced),
//                   PRE-SCALED by S128.
//  blocks 160..287: WnT/W1T/W2T bf16 transposes.
// w3A layout (validated R6-R14):
//   w3A[pu*4096 + ks*512 + l*8 + i] = S128 * W3[ks*16+(l>>5)*8+i][pu*32+(l&31)]
// ---------------------------------------------------------------------------
__global__ __launch_bounds__(256)
void prep_all(const float* __restrict__ Wn, const float* __restrict__ W1,
              const float* __restrict__ W2, const float* __restrict__ W3,
              ushort* __restrict__ WnT, ushort* __restrict__ W1T,
              ushort* __restrict__ W2T, ushort* __restrict__ w3A) {
    __shared__ float tile[128][33];
    const int b = blockIdx.x;
    const int t = threadIdx.x;
    if (b < 160) {
        const int pu = b;
        // coalesced load: 2 threads per row, 16 floats each
        {
            int row = t >> 1, h = t & 1;
            const float* src = W3 + (size_t)row * 5120 + pu * 32 + h * 16;
            #pragma unroll
            for (int q = 0; q < 4; ++q) {
                float4 v = *(const float4*)(src + q * 4);
                float* d = &tile[row][h * 16 + q * 4];
                d[0] = v.x; d[1] = v.y; d[2] = v.z; d[3] = v.w;
            }
        }
        __syncthreads();
        #pragma unroll
        for (int s = 0; s < 2; ++s) {
            int slot = s * 256 + t;          // 0..511
            int ks = slot >> 6, l = slot & 63;
            int m = l & 31;
            int kbase = ks * 16 + (l >> 5) * 8;
            bf16x8 v;
            #pragma unroll
            for (int i = 0; i < 8; ++i)
                v[i] = (short)f2b(tile[kbase + i][m] * S128);
            *(bf16x8*)&w3A[((size_t)(pu * 8 + ks) * 64 + l) * 8] = v;
        }
    } else {
        int idx = (b - 160) * 256 + t;       // 0..32767
        if (idx < 4096) {
            int n = idx >> 7, k = idx & 127;
            WnT[n * 128 + k] = f2b(Wn[k * 32 + n]);
        } else if (idx < 16384) {
            int tt = idx - 4096; int n = tt / 96, k = tt - n * 96;
            W1T[n * 96 + k] = f2b(W1[k * 128 + n]);
        } else {
            int tt = idx - 16384; int n = tt >> 7, k = tt & 127;
            W2T[n * 128 + k] = f2b(W2[k * 128 + n]);
        }
    }
}

// ---------------------------------------------------------------------------
// MEGA8 (unchanged from R14 champion): monolithic, B from LDS, per-unit a[8],
// (512,6), x2f stride 130 + float2 tail, pre-scaled w3A.
// ---------------------------------------------------------------------------
__global__ __launch_bounds__(512, 6)
void mega8(const float* __restrict__ ef,  const float* __restrict__ em2,
           const float* __restrict__ nfs, const float* __restrict__ nfr,
           const ushort* __restrict__ WnT, const ushort* __restrict__ W1T,
           const ushort* __restrict__ W2T, const ushort* __restrict__ w3A,
           ushort* __restrict__ dt)
{
    __shared__ __align__(16) ushort scratch[16640]; // 33280 B: scal|h1b, later x2f
    __shared__ __align__(16) ushort hbuf[64 * 128]; // 16384 B: h2 XOR-swizzled

    const int tid  = threadIdx.x;
    const int lane = tid & 63, wv = tid >> 6;
    const int l15  = lane & 15, lg = lane >> 4;
    const int e0   = blockIdx.x * 64;

    ushort* scal = scratch;          // [64][104]
    ushort* h1b  = scratch + 6656;   // [64][136]
    float*  x2f  = (float*)scratch;  // [64][130] fragment-order (after MLP)

    // ---------- ef -> scal cols 64..95 ----------
    #pragma unroll
    for (int q = 0; q < 4; ++q) {
        int idx = q * 512 + tid;         // 0..2047
        int e = idx >> 5, j = idx & 31;
        scal[e * 104 + 64 + j] = f2b(ef[(size_t)(e0 + e) * 32 + j]);
    }

    // ---------- MLP step 1: s_send/s_recv = nf @ Wn * S128 ----------
    {
        const int h = wv >> 2, eb = (wv & 3) * 16;
        const float* src = h ? nfr : nfs;
        const size_t erow = (size_t)(e0 + eb + l15) * 128;
        f32x4 acc1[2] = {{0,0,0,0},{0,0,0,0}};
        #pragma unroll
        for (int ks = 0; ks < 4; ++ks) {
            float4 va = *(const float4*)(src + erow + ks * 32 + lg * 8);
            float4 vb = *(const float4*)(src + erow + ks * 32 + lg * 8 + 4);
            bf16x8 a;
            a[0]=(short)f2b(va.x); a[1]=(short)f2b(va.y);
            a[2]=(short)f2b(va.z); a[3]=(short)f2b(va.w);
            a[4]=(short)f2b(vb.x); a[5]=(short)f2b(vb.y);
            a[6]=(short)f2b(vb.z); a[7]=(short)f2b(vb.w);
            #pragma unroll
            for (int nf = 0; nf < 2; ++nf) {
                bf16x8 b = *(const bf16x8*)(WnT + (nf * 16 + l15) * 128 + ks * 32 + lg * 8);
                acc1[nf] = __builtin_amdgcn_mfma_f32_16x16x32_bf16(a, b, acc1[nf], 0, 0, 0);
            }
        }
        #pragma unroll
        for (int nf = 0; nf < 2; ++nf)
            #pragma unroll
            for (int r = 0; r < 4; ++r)
                scal[(eb + lg * 4 + r) * 104 + h * 32 + nf * 16 + l15] =
                    f2b(acc1[nf][r] * S128);
    }
    __syncthreads();

    // ---------- MLP step 2: h1 = silu(scal @ W1 * S96) ----------
    {
        const int et = wv & 3, nh = wv >> 2;
        f32x4 acc2[4] = {{0,0,0,0},{0,0,0,0},{0,0,0,0},{0,0,0,0}};
        #pragma unroll
        for (int ks = 0; ks < 3; ++ks) {
            bf16x8 a = *(const bf16x8*)&scal[(et * 16 + l15) * 104 + ks * 32 + lg * 8];
            #pragma unroll
            for (int nf = 0; nf < 4; ++nf) {
                int gn = nh * 4 + nf;
                bf16x8 b = *(const bf16x8*)(W1T + (gn * 16 + l15) * 96 + ks * 32 + lg * 8);
                acc2[nf] = __builtin_amdgcn_mfma_f32_16x16x32_bf16(a, b, acc2[nf], 0, 0, 0);
            }
        }
        #pragma unroll
        for (int nf = 0; nf < 4; ++nf)
            #pragma unroll
            for (int r = 0; r < 4; ++r)
                h1b[(et * 16 + lg * 4 + r) * 136 + (nh * 4 + nf) * 16 + l15] =
                    f2b(silu_f(acc2[nf][r] * S96));
    }
    __syncthreads();

    // ---------- MLP step 3: h2 = silu(h1 @ W2 * S128) -> hbuf XOR-swizzled ----------
    {
        const int et = wv & 3, nh = wv >> 2;
        f32x4 acc3[4] = {{0,0,0,0},{0,0,0,0},{0,0,0,0},{0,0,0,0}};
        #pragma unroll
        for (int ks = 0; ks < 4; ++ks) {
            bf16x8 a = *(const bf16x8*)&h1b[(et * 16 + l15) * 136 + ks * 32 + lg * 8];
            #pragma unroll
            for (int nf = 0; nf < 4; ++nf) {
                int gn = nh * 4 + nf;
                bf16x8 b = *(const bf16x8*)(W2T + (gn * 16 + l15) * 128 + ks * 32 + lg * 8);
                acc3[nf] = __builtin_amdgcn_mfma_f32_16x16x32_bf16(a, b, acc3[nf], 0, 0, 0);
            }
        }
        __syncthreads();   // all h1b/scal reads done before scratch reuse
        #pragma unroll
        for (int nf = 0; nf < 4; ++nf)
            #pragma unroll
            for (int r = 0; r < 4; ++r) {
                int e = et * 16 + lg * 4 + r;
                int col = (nh * 4 + nf) * 16 + l15;
                hbuf[e * 128 + (col ^ ((e & 15) << 3))] =
                    f2b(silu_f(acc3[nf][r] * S128));
            }
    }

    // ---------- stage x2 (em2) as f32 fragment-order into x2f[e][130] ----------
    {
        int e = tid >> 3, grp = tid & 7;
        const float* xr = em2 + (size_t)(e0 + e) * 128;
        float* dst = &x2f[e * 130];
        #pragma unroll
        for (int r = 0; r < 16; ++r) {
            int idx = grp * 16 + r;
            int reg = idx & 15;
            int vb = (reg & 3) + 8 * (reg >> 2);
            float val;
            if (idx < 32) {
                int hi2 = idx >> 4;
                val = xr[vb + 4 * hi2];
            } else {
                int slot = (idx - 32) >> 4;
                int j = slot >> 1, hi2 = slot & 1;
                val = xr[32 + (vb + 4 * hi2) * 3 + j];
            }
            dst[idx] = val;
        }
    }
    __syncthreads();

    // ---------- GEMM: per-unit a[8], B from LDS, float2 f32 tail ----------
    const int el  = lane & 31;
    const int hi  = lane >> 5;
    const int sw0 = (el & 15) << 3;
    const float* x2r0 = &x2f[el * 130];
    const float* x2r1 = &x2f[(32 + el) * 130];

    #pragma unroll 1
    for (int un = 0; un < 20; ++un) {
        const int pu = un * 8 + wv;          // wave-uniform
        const int p = pu >> 5, u = pu & 31;
        const ushort* Ab = w3A + (size_t)pu * 4096 + lane * 8;

        bf16x8 a[8];
        #pragma unroll
        for (int ks = 0; ks < 8; ++ks)
            a[ks] = *(const bf16x8*)(Ab + ks * 512);

        #pragma unroll 1
        for (int eh = 0; eh < 2; ++eh) {
            const ushort* hrow = &hbuf[(eh * 32 + el) * 128];
            f32x16 acc = {0,0,0,0,0,0,0,0,0,0,0,0,0,0,0,0};
            #pragma unroll
            for (int ks = 0; ks < 8; ++ks) {
                bf16x8 b = *(const bf16x8*)&hrow[(ks * 16 + hi * 8) ^ sw0];
                acc = __builtin_amdgcn_mfma_f32_32x32x16_bf16(a[ks], b, acc, 0, 0, 0);
            }
            const float* xr = eh ? x2r1 : x2r0;
            const int ecol = e0 + eh * 32 + el;
            if (p == 0 || p == 2) {
                float s = 0.f;
                #pragma unroll
                for (int g = 0; g < 8; ++g) {
                    float2 q = *(const float2*)&xr[hi * 16 + g * 2];
                    s += acc[2*g] * q.x + acc[2*g+1] * q.y;
                }
                s += __shfl_xor(s, 32);
                if (hi == 0)
                    dt[(size_t)(((p == 0) ? 0 : 128) + u) * NE + ecol] = f2b(s);
            } else {
                const int row0 = ((p == 1) ? 32 : (p == 3) ? 160 : 256) + u * 3;
                #pragma unroll
                for (int j = 0; j < 3; ++j) {
                    float s = 0.f;
                    #pragma unroll
                    for (int g = 0; g < 8; ++g) {
                        float2 q = *(const float2*)&xr[32 + (j * 2 + hi) * 16 + g * 2];
                        s += acc[2*g] * q.x + acc[2*g+1] * q.y;
                    }
                    s += __shfl_xor(s, 32);
                    if (hi == 0)
                        dt[(size_t)(row0 + j) * NE + ecol] = f2b(s);
                }
            }
        }
    }
}

// ---------------------------------------------------------------------------
// FINALIZE2: d_t + em1 -> c-values -> output matmuls. 32 edges/block, 4 waves.
// ---------------------------------------------------------------------------
__global__ __launch_bounds__(256)
void finalize2(const float* __restrict__ em1, const ushort* __restrict__ dt,
               const float* __restrict__ W0e, const float* __restrict__ W1o,
               const float* __restrict__ W1e, float* __restrict__ out)
{
    __shared__ __align__(16) ushort dl[352 * 33];   // 23232 B
    __shared__ __align__(16) ushort x1b[32 * 132];  // 8448 B
    const int tid  = threadIdx.x;
    const int lane = tid & 63, wv = tid >> 6;
    const int l15  = lane & 15, lg = lane >> 4;
    const int eb   = blockIdx.x * 32;

    for (int idx = tid; idx < 352 * 32; idx += 256) {
        int row = idx >> 5, e = idx & 31;
        dl[row * 33 + e] = dt[(size_t)row * NE + eb + e];
    }
    {
        int e = tid >> 3, seg = tid & 7;
        const float* x1 = em1 + (size_t)(eb + e) * 128 + seg * 16;
        #pragma unroll
        for (int q = 0; q < 4; ++q) {
            float4 v = *(const float4*)(x1 + q * 4);
            *(uint*)&x1b[e * 132 + seg * 16 + q * 4]     = packbf(v.x, v.y);
            *(uint*)&x1b[e * 132 + seg * 16 + q * 4 + 2] = packbf(v.z, v.w);
        }
    }
    __syncthreads();

    #pragma unroll 1
    for (int it = 0; it < 4; ++it) {
        int unit = it * 4 + wv;
        if (unit >= 14) break;
        int mi = unit & 1, task = unit >> 1;
        const int ei = mi * 16 + l15;
        const ushort* xe = &x1b[ei * 132];
        const size_t orow = (size_t)(eb + mi * 16 + lg * 4) * 224;

        if (task == 0) {                       // out_0e: K = [c1|c4]
            bf16x8 af0, af1;
            #pragma unroll
            for (int t = 0; t < 8; ++t) {
                int u = lg * 8 + t;
                af0[t] = (short)f2b(S32 * b2f(xe[u]) * b2f(dl[u * 33 + ei]));
                float c4 = 0.f;
                #pragma unroll
                for (int i = 0; i < 3; ++i)
                    c4 += b2f(xe[32 + u * 3 + i]) * b2f(dl[(160 + u * 3 + i) * 33 + ei]);
                af1[t] = (short)f2b(c4 * S96);
            }
            #pragma unroll
            for (int nf = 0; nf < 2; ++nf) {
                bf16x8 bf0, bf1;
                #pragma unroll
                for (int t = 0; t < 8; ++t) {
                    bf0[t] = (short)f2b(W0e[(lg * 8 + t) * 32 + nf * 16 + l15]);
                    bf1[t] = (short)f2b(W0e[(32 + lg * 8 + t) * 32 + nf * 16 + l15]);
                }
                f32x4 o = {0.f, 0.f, 0.f, 0.f};
                o = __builtin_amdgcn_mfma_f32_16x16x32_bf16(af0, bf0, o, 0, 0, 0);
                o = __builtin_amdgcn_mfma_f32_16x16x32_bf16(af1, bf1, o, 0, 0, 0);
                #pragma unroll
                for (int rr = 0; rr < 4; ++rr)
                    out[orow + (size_t)rr * 224 + nf * 16 + l15] = o[rr] * S64;
            }
        } else if (task <= 3) {                // out_1o, j = task-1: K = [c2|c3]
            int j = task - 1;
            bf16x8 af0, af1;
            #pragma unroll
            for (int t = 0; t < 8; ++t) {
                int u = lg * 8 + t;
                af0[t] = (short)f2b(S32 * b2f(xe[u]) * b2f(dl[(32 + u * 3 + j) * 33 + ei]));
                af1[t] = (short)f2b(S32 * b2f(xe[32 + u * 3 + j]) * b2f(dl[(128 + u) * 33 + ei]));
            }
            #pragma unroll
            for (int nf = 0; nf < 2; ++nf) {
                bf16x8 bf0, bf1;
                #pragma unroll
                for (int t = 0; t < 8; ++t) {
                    bf0[t] = (short)f2b(W1o[(lg * 8 + t) * 32 + nf * 16 + l15]);
                    bf1[t] = (short)f2b(W1o[(32 + lg * 8 + t) * 32 + nf * 16 + l15]);
                }
                f32x4 o = {0.f, 0.f, 0.f, 0.f};
                o = __builtin_amdgcn_mfma_f32_16x16x32_bf16(af0, bf0, o, 0, 0, 0);
                o = __builtin_amdgcn_mfma_f32_16x16x32_bf16(af1, bf1, o, 0, 0, 0);
                #pragma unroll
                for (int rr = 0; rr < 4; ++rr)
                    out[orow + (size_t)rr * 224 + 32 + (nf * 16 + l15) * 3 + j] = o[rr] * S64;
            }
        } else {                               // out_1e, k = task-4: K = c5
            int k = task - 4;
            int k1 = k + 1; if (k1 > 2) k1 -= 3;
            int k2 = k + 2; if (k2 > 2) k2 -= 3;
            bf16x8 af0;
            #pragma unroll
            for (int t = 0; t < 8; ++t) {
                int u = lg * 8 + t;
                float a_ = b2f(xe[32 + u * 3 + k1]) * b2f(dl[(256 + u * 3 + k2) * 33 + ei])
                         - b2f(xe[32 + u * 3 + k2]) * b2f(dl[(256 + u * 3 + k1) * 33 + ei]);
                af0[t] = (short)f2b(a_ * S64);
            }
            #pragma unroll
            for (int nf = 0; nf < 2; ++nf) {
                bf16x8 bf0;
                #pragma unroll
                for (int t = 0; t < 8; ++t)
                    bf0[t] = (short)f2b(W1e[(lg * 8 + t) * 32 + nf * 16 + l15]);
                f32x4 o = {0.f, 0.f, 0.f, 0.f};
                o = __builtin_amdgcn_mfma_f32_16x16x32_bf16(af0, bf0, o, 0, 0, 0);
                #pragma unroll
                for (int rr = 0; rr < 4; ++rr)
                    out[orow + (size_t)rr * 224 + 128 + (nf * 16 + l15) * 3 + k] = o[rr] * S32;
            }
        }
    }
}

// ---------------------------------------------------------------------------
extern "C" void kernel_launch(void* const* d_in, const int* in_sizes, int n_in,
                              void* d_out, int out_size, void* d_ws, size_t ws_size,
                              hipStream_t stream) {
    const float* ef  = (const float*)d_in[0];
    const float* em1 = (const float*)d_in[1];
    const float* em2 = (const float*)d_in[2];
    const float* nfs = (const float*)d_in[3];
    const float* nfr = (const float*)d_in[4];
    const float* Wn  = (const float*)d_in[5];
    const float* W1  = (const float*)d_in[6];
    const float* W2  = (const float*)d_in[7];
    const float* W3  = (const float*)d_in[8];
    const float* W0e = (const float*)d_in[9];
    const float* W1o = (const float*)d_in[10];
    const float* W1e = (const float*)d_in[11];
    float* out = (float*)d_out;

    const int E = in_sizes[0] / 32;   // 40000

    // ws: w3A [160*8*64*8] | WnT | W1T | W2T | d_t [352][E]
    char* ws = (char*)d_ws;
    ushort* w3A = (ushort*)ws;
    size_t off = (size_t)5120 * 128 * 2;
    ushort* WnT = (ushort*)(ws + off);  off += 32 * 128 * 2;
    ushort* W1T = (ushort*)(ws + off);  off += 128 * 96 * 2;
    ushort* W2T = (ushort*)(ws + off);  off += 128 * 128 * 2;
    ushort* dt  = (ushort*)(ws + off);  // 352 * E * 2 = 28.2 MB

    prep_all<<<288, 256, 0, stream>>>(Wn, W1, W2, W3, WnT, W1T, W2T, w3A);
    mega8<<<E / 64, 512, 0, stream>>>(ef, em2, nfs, nfr,
                                      WnT, W1T, W2T, w3A, dt);
    finalize2<<<E / 32, 256, 0, stream>>>(em1, dt, W0e, W1o, W1e, out);
}